// Round 1
// baseline (17989.124 us; speedup 1.0000x reference)
//
#include <hip/hip_runtime.h>

#define T_DIM 2048
#define B_DIM 16
#define H_DIM 1024
#define C3    3072

// ---------------- ws layout (float elements) ----------------
// x    : [T][B][3072]   normalized input projections (384 MB)
// wp   : [256][1024][16] packed gamma*(w_hh - meanrow) , k-major, 12 rows + 4 zero pad (16 MB)
// msum : [2][1024]      column sums of w_hh groups
// hbuf : [2][16][1024]  ping-pong hidden state
static const size_t X_ELEMS  = (size_t)T_DIM * B_DIM * C3;   // 100663296
static const size_t WP_OFF   = X_ELEMS;
static const size_t WP_ELEMS = 256ull * 1024 * 16;           // 4194304
static const size_t MS_OFF   = WP_OFF + WP_ELEMS;
static const size_t HB_OFF   = MS_OFF + 2048;

// ============ K1: column sums of w_hh per LN group ============
__global__ __launch_bounds__(256) void k_colsum(const float* __restrict__ w_hh,
                                                float* __restrict__ msum)
{
    int k  = blockIdx.x * 256 + threadIdx.x;   // gridDim.x == 4 -> k in [0,1024)
    int rc = blockIdx.y;                       // 0..11 row chunks of 256
    const float* p = w_hh + (size_t)rc * 256 * H_DIM + k;
    float s = 0.f;
    #pragma unroll 8
    for (int r = 0; r < 256; ++r) s += p[(size_t)r * H_DIM];
    atomicAdd(&msum[(rc < 8 ? 0 : 1) * H_DIM + k], s);
}

// ============ K2: pack W'' = gamma*(w_hh - meanrow) , k-major blocks ============
__global__ __launch_bounds__(256) void k_pack(const float* __restrict__ w_hh,
                                              const float* __restrict__ gamma_hh,
                                              const float* __restrict__ msum,
                                              float* __restrict__ wp)
{
    int k   = blockIdx.y * 256 + threadIdx.x;  // 0..1023
    int jsl = blockIdx.x;                      // 0..255 (4 j's each)
    float m_rz = msum[k]        * (1.f / 2048.f);
    float m_n  = msum[H_DIM + k] * (1.f / 1024.f);
    float o[16];
    #pragma unroll
    for (int g = 0; g < 3; ++g) {
        float mg = (g < 2) ? m_rz : m_n;
        #pragma unroll
        for (int i = 0; i < 4; ++i) {
            int c = g * H_DIM + jsl * 4 + i;
            o[g * 4 + i] = gamma_hh[c] * (w_hh[(size_t)c * H_DIM + k] - mg);
        }
    }
    o[12] = o[13] = o[14] = o[15] = 0.f;
    float* dst = wp + ((size_t)jsl * 1024 + k) * 16;
    #pragma unroll
    for (int q = 0; q < 4; ++q)
        *(float4*)(dst + q * 4) = make_float4(o[q*4+0], o[q*4+1], o[q*4+2], o[q*4+3]);
}

// ============ K3: proj = xs @ w_ih^T , f32, out layout [T][B][3072] ============
#define BM 128
#define BN 64
#define BK 32
__global__ __launch_bounds__(256) void k_gemm(const float* __restrict__ A,   // xs [32768][1024]
                                              const float* __restrict__ Bw,  // w_ih [3072][1024]
                                              float* __restrict__ X)
{
    __shared__ float As[BK][BM + 4];
    __shared__ float Bs[BK][BN + 4];
    int n0 = blockIdx.x * BN;      // gridDim.x = 48
    int m0 = blockIdx.y * BM;      // gridDim.y = 256
    int tid = threadIdx.x;
    int tx = tid & 15, ty = tid >> 4;
    float acc[8][4];
    #pragma unroll
    for (int i = 0; i < 8; ++i)
        #pragma unroll
        for (int j = 0; j < 4; ++j) acc[i][j] = 0.f;

    for (int k0 = 0; k0 < 1024; k0 += BK) {
        #pragma unroll
        for (int p = 0; p < 4; ++p) {           // A tile: 128x32
            int id = tid + p * 256;
            int r = id >> 3, c4 = (id & 7) * 4;
            float4 v = *(const float4*)&A[(size_t)(m0 + r) * 1024 + k0 + c4];
            As[c4 + 0][r] = v.x; As[c4 + 1][r] = v.y;
            As[c4 + 2][r] = v.z; As[c4 + 3][r] = v.w;
        }
        #pragma unroll
        for (int p = 0; p < 2; ++p) {           // B tile: 64x32
            int id = tid + p * 256;
            int r = id >> 3, c4 = (id & 7) * 4;
            float4 v = *(const float4*)&Bw[(size_t)(n0 + r) * 1024 + k0 + c4];
            Bs[c4 + 0][r] = v.x; Bs[c4 + 1][r] = v.y;
            Bs[c4 + 2][r] = v.z; Bs[c4 + 3][r] = v.w;
        }
        __syncthreads();
        #pragma unroll
        for (int kk = 0; kk < BK; ++kk) {
            float4 a0 = *(const float4*)&As[kk][ty * 8];
            float4 a1 = *(const float4*)&As[kk][ty * 8 + 4];
            float4 b0 = *(const float4*)&Bs[kk][tx * 4];
            float a[8] = {a0.x, a0.y, a0.z, a0.w, a1.x, a1.y, a1.z, a1.w};
            float b[4] = {b0.x, b0.y, b0.z, b0.w};
            #pragma unroll
            for (int i = 0; i < 8; ++i)
                #pragma unroll
                for (int j = 0; j < 4; ++j) acc[i][j] += a[i] * b[j];
        }
        __syncthreads();
    }
    #pragma unroll
    for (int i = 0; i < 8; ++i) {
        int m = m0 + ty * 8 + i;
        int tt = m & (T_DIM - 1), bb = m >> 11;
        float4 v = make_float4(acc[i][0], acc[i][1], acc[i][2], acc[i][3]);
        *(float4*)&X[((size_t)tt * B_DIM + bb) * C3 + n0 + tx * 4] = v;
    }
}

// ============ K4: in-place _ln_x on each 3072-row: rz(2048, var/2047), n(1024, var/1023) ============
__device__ __forceinline__ float block_sum_256(float v, float* sb)
{
    #pragma unroll
    for (int o = 32; o > 0; o >>= 1) v += __shfl_down(v, o, 64);
    int lane = threadIdx.x & 63, wid = threadIdx.x >> 6;
    if (lane == 0) sb[wid] = v;
    __syncthreads();
    float r = (sb[0] + sb[1]) + (sb[2] + sb[3]);
    __syncthreads();
    return r;
}

__global__ __launch_bounds__(256) void k_ln(float* __restrict__ X,
                                            const float* __restrict__ gamma,
                                            const float* __restrict__ beta)
{
    __shared__ float sb[4];
    float* p = X + (size_t)blockIdx.x * C3;
    int tid = threadIdx.x;
    float v[8], w[4];
    float4 t0 = *(float4*)&p[tid * 8];
    float4 t1 = *(float4*)&p[tid * 8 + 4];
    v[0]=t0.x; v[1]=t0.y; v[2]=t0.z; v[3]=t0.w;
    v[4]=t1.x; v[5]=t1.y; v[6]=t1.z; v[7]=t1.w;
    float4 t2 = *(float4*)&p[2048 + tid * 4];
    w[0]=t2.x; w[1]=t2.y; w[2]=t2.z; w[3]=t2.w;

    float s = 0.f;
    #pragma unroll
    for (int i = 0; i < 8; ++i) s += v[i];
    float mean = block_sum_256(s, sb) * (1.f / 2048.f);
    float ss = 0.f;
    #pragma unroll
    for (int i = 0; i < 8; ++i) { float d = v[i] - mean; ss += d * d; }
    float inv = rsqrtf(block_sum_256(ss, sb) * (1.f / 2047.f));
    #pragma unroll
    for (int i = 0; i < 8; ++i) {
        int c = tid * 8 + i;
        v[i] = gamma[c] * (v[i] - mean) * inv + beta[c];
    }
    *(float4*)&p[tid * 8]     = make_float4(v[0], v[1], v[2], v[3]);
    *(float4*)&p[tid * 8 + 4] = make_float4(v[4], v[5], v[6], v[7]);

    float sn = (w[0] + w[1]) + (w[2] + w[3]);
    float mn = block_sum_256(sn, sb) * (1.f / 1024.f);
    float ssn = 0.f;
    #pragma unroll
    for (int i = 0; i < 4; ++i) { float d = w[i] - mn; ssn += d * d; }
    float invn = rsqrtf(block_sum_256(ssn, sb) * (1.f / 1023.f));
    #pragma unroll
    for (int i = 0; i < 4; ++i) {
        int c = 2048 + tid * 4 + i;
        w[i] = gamma[c] * (w[i] - mn) * invn + beta[c];
    }
    *(float4*)&p[2048 + tid * 4] = make_float4(w[0], w[1], w[2], w[3]);
}

// ============ K5: one GRU timestep (LN pre-folded into wp) ============
// grid 512 = 256 jslices x 2 batch-halves; 256 threads.
// hlds row: 32 chunks of 32 floats padded to 36 -> conflict-free strided b128 reads.
__device__ __forceinline__ int hcol(int k) { return k + ((k >> 5) << 2); }

#define FMA4(wv, hx, bi) \
    acc[0][bi] += wv.x * (hx); acc[1][bi] += wv.y * (hx); \
    acc[2][bi] += wv.z * (hx); acc[3][bi] += wv.w * (hx);

__global__ __launch_bounds__(256) void k_step(const float* __restrict__ X,
                                              const float* __restrict__ wp,
                                              const float* __restrict__ b_hh,
                                              const float* __restrict__ h_in,
                                              float* __restrict__ h_out,
                                              float* __restrict__ ys,
                                              int t)
{
    __shared__ float hlds[8][1152];     // 8 batches x swizzled 1024
    __shared__ float red[32][8][17];    // k-split partials
    __shared__ float dotb[12][9];       // gathered dots [gate*4+jl][b]

    int bid = blockIdx.x;
    int jsl = bid >> 1;
    int bh  = bid & 1;
    int js  = jsl * 4;
    int b0  = bh * 8;
    int tid = threadIdx.x;

    // stage h slice: 8 x 1024 floats
    {
        const float4* src = (const float4*)(h_in + (size_t)b0 * H_DIM);
        #pragma unroll
        for (int i = 0; i < 8; ++i) {
            int idx = tid + i * 256;          // f4 index
            float4 v = src[idx];
            int b = idx >> 8, k = (idx & 255) * 4;
            *(float4*)&hlds[b][hcol(k)] = v;
        }
    }
    __syncthreads();

    // thread = (cq[gate] 0..3, bq 0..1, ks 0..31); 4x4 microtile, K range 32
    int cq = tid & 3, bq = (tid >> 2) & 1, ks = tid >> 3;
    float acc[4][4];
    #pragma unroll
    for (int i = 0; i < 4; ++i)
        #pragma unroll
        for (int j = 0; j < 4; ++j) acc[i][j] = 0.f;

    const float4* wrow = (const float4*)(wp + ((size_t)jsl * 1024 + ks * 32) * 16) + cq;
    int colb = ks * 36;   // hcol(ks*32)
    #pragma unroll
    for (int kk = 0; kk < 32; kk += 4) {
        float4 w0 = wrow[(kk + 0) * 4];
        float4 w1 = wrow[(kk + 1) * 4];
        float4 w2 = wrow[(kk + 2) * 4];
        float4 w3 = wrow[(kk + 3) * 4];
        int col = colb + kk;
        float4 hA = *(const float4*)&hlds[bq * 4 + 0][col];
        float4 hB = *(const float4*)&hlds[bq * 4 + 1][col];
        float4 hC = *(const float4*)&hlds[bq * 4 + 2][col];
        float4 hD = *(const float4*)&hlds[bq * 4 + 3][col];
        FMA4(w0, hA.x, 0) FMA4(w0, hB.x, 1) FMA4(w0, hC.x, 2) FMA4(w0, hD.x, 3)
        FMA4(w1, hA.y, 0) FMA4(w1, hB.y, 1) FMA4(w1, hC.y, 2) FMA4(w1, hD.y, 3)
        FMA4(w2, hA.z, 0) FMA4(w2, hB.z, 1) FMA4(w2, hC.z, 2) FMA4(w2, hD.z, 3)
        FMA4(w3, hA.w, 0) FMA4(w3, hB.w, 1) FMA4(w3, hC.w, 2) FMA4(w3, hD.w, 3)
    }

    int tile = bq * 4 + cq;
    #pragma unroll
    for (int ci = 0; ci < 4; ++ci)
        #pragma unroll
        for (int bi = 0; bi < 4; ++bi)
            red[ks][tile][ci * 4 + bi] = acc[ci][bi];
    __syncthreads();

    if (tid < 96) {                  // 12 channels x 8 batches
        int cl = tid >> 3, bl = tid & 7;
        int gate = cl >> 2, jl = cl & 3;
        int tl = (bl >> 2) * 4 + gate;
        int el = jl * 4 + (bl & 3);
        float s = 0.f;
        #pragma unroll
        for (int q = 0; q < 32; ++q) s += red[q][tl][el];
        s += b_hh[gate * H_DIM + js + jl];
        dotb[gate * 4 + jl][bl] = s;
    }
    __syncthreads();

    if (tid < 32) {                  // 4 j x 8 b gates
        int jl = tid >> 3, bl = tid & 7;
        int b = b0 + bl;
        int j = js + jl;
        const float* xr = X + ((size_t)t * B_DIM + b) * C3;
        float r = 1.f / (1.f + __expf(-(xr[j] + dotb[jl][bl])));
        float z = 1.f / (1.f + __expf(-(xr[H_DIM + j] + dotb[4 + jl][bl])));
        float n = tanhf(xr[2 * H_DIM + j] + r * dotb[8 + jl][bl]);
        float hold = hlds[bl][hcol(j)];
        float hnew = (1.f - z) * n + z * hold;
        h_out[(size_t)b * H_DIM + j] = hnew;
        ys[((size_t)b * T_DIM + t) * H_DIM + j] = hnew;
    }
}

extern "C" void kernel_launch(void* const* d_in, const int* in_sizes, int n_in,
                              void* d_out, int out_size, void* d_ws, size_t ws_size,
                              hipStream_t stream)
{
    (void)in_sizes; (void)n_in; (void)out_size; (void)ws_size;
    const float* xs   = (const float*)d_in[0];
    const float* h0   = (const float*)d_in[1];
    const float* w_ih = (const float*)d_in[2];
    const float* w_hh = (const float*)d_in[3];
    const float* b_ih = (const float*)d_in[4];
    const float* b_hh = (const float*)d_in[5];
    const float* g_ih = (const float*)d_in[6];
    const float* g_hh = (const float*)d_in[7];
    float* out = (float*)d_out;
    float* ws  = (float*)d_ws;

    float* x    = ws;
    float* wp   = ws + WP_OFF;
    float* msum = ws + MS_OFF;
    float* hbuf = ws + HB_OFF;

    hipMemsetAsync(msum, 0, 2048 * sizeof(float), stream);
    k_colsum<<<dim3(4, 12), 256, 0, stream>>>(w_hh, msum);
    k_pack<<<dim3(256, 4), 256, 0, stream>>>(w_hh, g_hh, msum, wp);
    k_gemm<<<dim3(48, 256), 256, 0, stream>>>(xs, w_ih, x);
    k_ln<<<T_DIM * B_DIM, 256, 0, stream>>>(x, g_ih, b_ih);
    hipMemcpyAsync(hbuf, h0, (size_t)B_DIM * H_DIM * sizeof(float),
                   hipMemcpyDeviceToDevice, stream);
    for (int t = 0; t < T_DIM; ++t) {
        const float* hi = hbuf + (size_t)(t & 1) * B_DIM * H_DIM;
        float*       ho = hbuf + (size_t)((t + 1) & 1) * B_DIM * H_DIM;
        k_step<<<512, 256, 0, stream>>>(x, wp, b_hh, hi, ho, out, t);
    }
    hipMemcpyAsync(out + (size_t)B_DIM * T_DIM * H_DIM, hbuf,
                   (size_t)B_DIM * H_DIM * sizeof(float),
                   hipMemcpyDeviceToDevice, stream);
}